// Round 15
// baseline (65.830 us; speedup 1.0000x reference)
//
#include <hip/hip_runtime.h>
#include <cstdint>

#define NCOARSE 4000
#define NFINE   40000
#define DIM     128
#define GRES    8
#define CELLH   0.125f
#define CAP_F   160      // fine slots per cell (9 sigma; validated R8)
#define CHUNKS  5        // CAP_F / 32
#define FCAP    384      // flat candidate-list cap per home cell (27-box, lambda~211)
#define NB_B    128      // flat-list blocks (4 home cells each)
#define NB_F    157      // fine-scatter blocks (ceil(40000/256))
#define NB_Y    125      // Y-GEMM blocks (32 rows each)
#define NBUILD  (NB_B + NB_F + NB_Y)   // 410

__device__ __forceinline__ uint64_t min64(uint64_t a, uint64_t b) { return a < b ? a : b; }
__device__ __forceinline__ uint64_t max64(uint64_t a, uint64_t b) { return a > b ? a : b; }
__device__ __forceinline__ int cell_coord(float x) {
    int c = (int)(x * 8.0f);
    return c < 0 ? 0 : (c > 7 ? 7 : c);
}

// ---------------- zero cntF (512 ints) ----------------
__global__ __launch_bounds__(256) void k_zero(int* __restrict__ p) {
    p[blockIdx.x * 256 + threadIdx.x] = 0;
}

// ------- build: flat lists (unsorted) + fine scatter + Y = xc @ W -------
union BuildSM {
    uint16_t cellS[4096];    // 8 KB  (flat-list part)
    float    xs[32][DIM];    // 16 KB (Y-GEMM part)
};

__global__ __launch_bounds__(256) void k_build(const float* __restrict__ pc,
                                               const float* __restrict__ pf,
                                               const float* __restrict__ xc,
                                               const float* __restrict__ W,
                                               int*    __restrict__ cntF,
                                               int*    __restrict__ nbrCnt,
                                               float4* __restrict__ srtF,
                                               float4* __restrict__ flatC,
                                               float*  __restrict__ Y) {
    __shared__ BuildSM sm;
    const int bid = blockIdx.x, tid = threadIdx.x;

    if (bid < NB_B) {
        // ---- flat 27-box candidate list for 4 home cells (1 wave each)
        #pragma unroll
        for (int t = 0; t < 16; ++t) {
            const int idx = t * 256 + tid;
            uint16_t cv = 0xFFFF;
            if (idx < NCOARSE)
                cv = (uint16_t)((cell_coord(pc[3*idx+2]) << 6) |
                                (cell_coord(pc[3*idx+1]) << 3) |
                                 cell_coord(pc[3*idx]));
            sm.cellS[idx] = cv;
        }
        __syncthreads();
        const int wid = tid >> 6, lane = tid & 63;
        const int hc = bid * 4 + wid;
        const int hx = hc & 7, hy = (hc >> 3) & 7, hz = hc >> 6;
        const int bx0 = max(hx-1,0), bx1 = min(hx+1,7);
        const int by0 = max(hy-1,0), by1 = min(hy+1,7);
        const int bz0 = max(hz-1,0), bz1 = min(hz+1,7);
        int off = 0;
        for (int it = 0; it < 63; ++it) {
            const int j = it * 64 + lane;
            const uint16_t cid = sm.cellS[j];
            const int cx = cid & 7, cy = (cid >> 3) & 7, cz = cid >> 6;
            const bool in = (j < NCOARSE) && cx >= bx0 && cx <= bx1 &&
                            cy >= by0 && cy <= by1 && cz >= bz0 && cz <= bz1;
            const unsigned long long mask = __ballot(in);
            if (in) {
                const int d = off + (int)__popcll(mask & ((1ull << lane) - 1ull));
                if (d < FCAP)
                    flatC[hc * FCAP + d] =
                        make_float4(pc[3*j], pc[3*j+1], pc[3*j+2], __int_as_float(j));
            }
            off += (int)__popcll(mask);
        }
        if (lane == 0) nbrCnt[hc] = off;     // write-once
    } else if (bid < NB_B + NB_F) {
        // ---- fine scatter into per-cell buckets (atomic; cntF pre-zeroed)
        const int j = (bid - NB_B) * 256 + tid;
        if (j < NFINE) {
            const float x = pf[3*j], y = pf[3*j+1], z = pf[3*j+2];
            const int c = (cell_coord(z) << 6) | (cell_coord(y) << 3) | cell_coord(x);
            const int slot = atomicAdd(&cntF[c], 1);
            if (slot < CAP_F) srtF[c * CAP_F + slot] = make_float4(x, y, z, __int_as_float(j));
        }
    } else {
        // ---- Y-GEMM tile: 32 rows x 128 cols
        const int g  = bid - (NB_B + NB_F);
        const int r0 = g * 32;
        #pragma unroll
        for (int t = 0; t < 4; ++t)
            reinterpret_cast<float4*>(sm.xs)[tid + t * 256] =
                reinterpret_cast<const float4*>(xc + r0 * DIM)[tid + t * 256];
        __syncthreads();
        const int rq = tid >> 5;
        const int jq = tid & 31;
        float acc[4][4];
        #pragma unroll
        for (int i = 0; i < 4; ++i)
            #pragma unroll
            for (int j = 0; j < 4; ++j) acc[i][j] = 0.f;
        #pragma unroll 2
        for (int k = 0; k < DIM; ++k) {
            const float4 wv = *reinterpret_cast<const float4*>(W + k * DIM + jq * 4);
            #pragma unroll
            for (int i = 0; i < 4; ++i) {
                const float a = sm.xs[rq + 8 * i][k];
                acc[i][0] += a * wv.x; acc[i][1] += a * wv.y;
                acc[i][2] += a * wv.z; acc[i][3] += a * wv.w;
            }
        }
        #pragma unroll
        for (int i = 0; i < 4; ++i)
            *reinterpret_cast<float4*>(Y + (r0 + rq + 8 * i) * DIM + jq * 4) =
                make_float4(acc[i][0], acc[i][1], acc[i][2], acc[i][3]);
    }
}

// ------- main: LDS-shared-list KNN + gather-mean of Y -------
__device__ __forceinline__ void popmin_merge(const uint64_t own[7], uint64_t mg[7]) {
    uint64_t a0 = own[0], a1 = own[1], a2 = own[2], a3 = own[3],
             a4 = own[4], a5 = own[5], a6 = own[6];
    #pragma unroll
    for (int r = 0; r < 7; ++r) {
        uint64_t m = a0;
        m = min64(m, __shfl_xor((unsigned long long)m, 1));
        m = min64(m, __shfl_xor((unsigned long long)m, 2));
        m = min64(m, __shfl_xor((unsigned long long)m, 4));
        mg[r] = m;
        const bool win = (a0 == m);
        a0 = win ? a1 : a0;
        a1 = win ? a2 : a1;
        a2 = win ? a3 : a2;
        a3 = win ? a4 : a3;
        a4 = win ? a5 : a4;
        a5 = win ? a6 : a5;
        a6 = win ? ~0ull : a6;
    }
}

__device__ __forceinline__ bool done_check(uint64_t k7, float fx, float fy, float fz,
                                           int ix, int iy, int iz, int s) {
    const float d7 = __uint_as_float((uint32_t)(k7 >> 32));
    float clear = 1e30f;
    if (ix - s >= 0) clear = fminf(clear, __fsub_rn(fx, (float)(ix - s) * CELLH));
    if (ix + s <= 6) clear = fminf(clear, __fsub_rn((float)(ix + s + 1) * CELLH, fx));
    if (iy - s >= 0) clear = fminf(clear, __fsub_rn(fy, (float)(iy - s) * CELLH));
    if (iy + s <= 6) clear = fminf(clear, __fsub_rn((float)(iy + s + 1) * CELLH, fy));
    if (iz - s >= 0) clear = fminf(clear, __fsub_rn(fz, (float)(iz - s) * CELLH));
    if (iz + s <= 6) clear = fminf(clear, __fsub_rn((float)(iz + s + 1) * CELLH, fz));
    return d7 < clear * clear * 0.9999f;   // NaN sentinel -> false
}

#define INS(p) { \
    const float ddx = __fsub_rn(fx, (p).x); \
    const float ddy = __fsub_rn(fy, (p).y); \
    const float ddz = __fsub_rn(fz, (p).z); \
    const float d2  = __fadd_rn(__fadd_rn(__fmul_rn(ddx, ddx), __fmul_rn(ddy, ddy)), \
                                __fmul_rn(ddz, ddz)); \
    const uint64_t v = ((uint64_t)__float_as_uint(d2) << 32) | (uint32_t)__float_as_uint((p).w); \
    if (v < own[6]) { \
        own[6] = min64(own[6], max64(own[5], v)); \
        own[5] = min64(own[5], max64(own[4], v)); \
        own[4] = min64(own[4], max64(own[3], v)); \
        own[3] = min64(own[3], max64(own[2], v)); \
        own[2] = min64(own[2], max64(own[1], v)); \
        own[1] = min64(own[1], max64(own[0], v)); \
        own[0] = min64(own[0], v); \
    } }

#define BRUTE() { \
    _Pragma("unroll") \
    for (int r = 0; r < 7; ++r) own[r] = ~0ull; \
    for (int i = par; i < NCOARSE; i += 8) { \
        const float4 p = make_float4(pc[3*i], pc[3*i+1], pc[3*i+2], __int_as_float(i)); \
        INS(p) \
    } }

__global__ __launch_bounds__(256) void k_main(
    const float*  __restrict__ Y,        // [4000][128] = xc @ W
    const float*  __restrict__ bias,
    const int*    __restrict__ cntF,
    const int*    __restrict__ nbrCnt,
    const float4* __restrict__ srtF,     // fine points bucketed by cell
    const float4* __restrict__ flatC,    // per-home-cell flat candidate lists
    const float*  __restrict__ pc,       // raw coarse positions (brute fallback)
    float* __restrict__ out)
{
    __shared__ float4 spts[FCAP];        // 6 KB

    const int tid  = threadIdx.x;
    const int bid  = blockIdx.x;
    const int cell = bid & 511;
    const int chunk= bid >> 9;

    const int ctot = min(cntF[cell], CAP_F);
    const int npts = min(32, ctot - chunk * 32);
    if (npts <= 0) return;                      // block-uniform

    const int fl  = tid >> 3;        // 0..31 local fine point
    const int par = tid & 7;         // lane within point-octet
    const bool active = fl < npts;
    const int ix = cell & 7, iy = (cell >> 3) & 7, iz = cell >> 6;

    const int total = nbrCnt[cell];             // uniform across block

    // stage the cell's candidate list once (coalesced), reused by all 32 points
    if (total <= FCAP) {
        const float4* fpts = flatC + cell * FCAP;
        for (int g = tid; g < total; g += 256) spts[g] = fpts[g];
    }
    __syncthreads();

    const float4 fp = srtF[cell * CAP_F + chunk * 32 + min(fl, npts - 1)];
    const float fx = fp.x, fy = fp.y, fz = fp.z;
    const int f = __float_as_int(fp.w);

    uint64_t own[7];
    #pragma unroll
    for (int r = 0; r < 7; ++r) own[r] = ~0ull;
    uint64_t mg[7];

    if (total <= FCAP) {
        // LDS scan: all octets read the same address each iter -> broadcast
        #pragma unroll 2
        for (int i = par; i < total; i += 8) { const float4 p = spts[i]; INS(p) }
        popmin_merge(own, mg);
        if (!done_check(mg[6], fx, fy, fz, ix, iy, iz, 1)) {   // ~never (P<1e-9/pt)
            BRUTE();
            popmin_merge(own, mg);
        }
    } else {                                     // flat list overflowed (~never)
        BRUTE();
        popmin_merge(own, mg);
    }

    // 6th/7th sqrt tie repair (reference sorts by f32 sqrt, stable) — uniform per octet
    int i5 = (int)(uint32_t)mg[5];
    {
        const int i6 = (int)(uint32_t)mg[6];
        const float d5 = sqrtf(__uint_as_float((uint32_t)(mg[5] >> 32)));
        const float d6 = sqrtf(__uint_as_float((uint32_t)(mg[6] >> 32)));
        if (d5 == d6 && i6 < i5) i5 = i6;
    }
    const int id0 = (int)(uint32_t)mg[0];
    const int id1 = (int)(uint32_t)mg[1];
    const int id2 = (int)(uint32_t)mg[2];
    const int id3 = (int)(uint32_t)mg[3];
    const int id4 = (int)(uint32_t)mg[4];
    const int id5 = i5;

    // epilogue: out[f] = mean(Y[idx6]) + b ; lane par covers 16 dims
    if (active) {
        constexpr float inv6 = 1.0f / 6.0f;
        #pragma unroll
        for (int k = 0; k < 4; ++k) {
            const int q = (k * 8 + par) * 4;
            const float4 y0 = *reinterpret_cast<const float4*>(Y + id0 * DIM + q);
            const float4 y1 = *reinterpret_cast<const float4*>(Y + id1 * DIM + q);
            const float4 y2 = *reinterpret_cast<const float4*>(Y + id2 * DIM + q);
            const float4 y3 = *reinterpret_cast<const float4*>(Y + id3 * DIM + q);
            const float4 y4 = *reinterpret_cast<const float4*>(Y + id4 * DIM + q);
            const float4 y5 = *reinterpret_cast<const float4*>(Y + id5 * DIM + q);
            const float4 bv = *reinterpret_cast<const float4*>(bias + q);
            float4 o;
            o.x = (y0.x + y1.x + y2.x + y3.x + y4.x + y5.x) * inv6 + bv.x;
            o.y = (y0.y + y1.y + y2.y + y3.y + y4.y + y5.y) * inv6 + bv.y;
            o.z = (y0.z + y1.z + y2.z + y3.z + y4.z + y5.z) * inv6 + bv.z;
            o.w = (y0.w + y1.w + y2.w + y3.w + y4.w + y5.w) * inv6 + bv.w;
            *reinterpret_cast<float4*>(out + f * DIM + q) = o;
        }
    }
}

extern "C" void kernel_launch(void* const* d_in, const int* in_sizes, int n_in,
                              void* d_out, int out_size, void* d_ws, size_t ws_size,
                              hipStream_t stream) {
    const float* xc = (const float*)d_in[0];
    const float* pc = (const float*)d_in[1];
    const float* pf = (const float*)d_in[2];
    const float* W  = (const float*)d_in[3];
    const float* b  = (const float*)d_in[4];
    float* out = (float*)d_out;

    // ws layout (bytes):
    //   0        cntF    512 ints (2048)
    //   2048     nbrCnt  512 ints (2048)
    //   4096     srtF    512*160 float4 (1310720)
    //   1314816  flatC   512*384 float4 (3145728)
    //   4460544  Y       4000*128 f32   (2048000)   total 6508544
    int*    cntF   = (int*)d_ws;
    int*    nbrCnt = (int*)((char*)d_ws + 2048);
    float4* srtF   = (float4*)((char*)d_ws + 4096);
    float4* flatC  = (float4*)((char*)d_ws + 1314816);
    float*  Y      = (float*)((char*)d_ws + 4460544);

    k_zero <<<dim3(2),            dim3(256), 0, stream>>>(cntF);
    k_build<<<dim3(NBUILD),       dim3(256), 0, stream>>>(pc, pf, xc, W, cntF, nbrCnt,
                                                          srtF, flatC, Y);
    k_main <<<dim3(512 * CHUNKS), dim3(256), 0, stream>>>(Y, b, cntF, nbrCnt,
                                                          srtF, flatC, pc, out);
}

// Round 16
// 48.719 us; speedup vs baseline: 1.3512x; 1.3512x over previous
//
#include <hip/hip_runtime.h>
#include <cstdint>

#define NCOARSE 4000
#define NFINE   40000
#define DIM     128
#define GRES    8
#define CELLH   0.125f
#define FCAP    384      // flat candidate-list cap per home cell (27-box, lambda~211)
#define NB_B    128      // flat-list blocks (4 home cells each)
#define NB_Y    125      // Y-GEMM blocks (32 rows each)
#define NBUILD  (NB_B + NB_Y)   // 253
#define LPP     16       // lanes per fine point

__device__ __forceinline__ uint64_t min64(uint64_t a, uint64_t b) { return a < b ? a : b; }
__device__ __forceinline__ uint64_t max64(uint64_t a, uint64_t b) { return a > b ? a : b; }
__device__ __forceinline__ int cell_coord(float x) {
    int c = (int)(x * 8.0f);
    return c < 0 ? 0 : (c > 7 ? 7 : c);
}

// ---------------- build: flat candidate lists + Y = xc @ W (identical to R12) ----
union BuildSM {
    uint16_t cellS[4096];    // 8 KB  (flat-list part)
    float    xs[32][DIM];    // 16 KB (Y-GEMM part)
};

__global__ __launch_bounds__(256) void k_build(const float* __restrict__ pc,
                                               const float* __restrict__ xc,
                                               const float* __restrict__ W,
                                               int*    __restrict__ nbrCnt,
                                               float4* __restrict__ flatC,
                                               float*  __restrict__ Y) {
    __shared__ BuildSM sm;
    const int bid = blockIdx.x, tid = threadIdx.x;

    if (bid < NB_B) {
        // ---- flat 27-box candidate list for 4 home cells (1 wave each)
        #pragma unroll
        for (int t = 0; t < 16; ++t) {
            const int idx = t * 256 + tid;
            uint16_t cv = 0xFFFF;
            if (idx < NCOARSE)
                cv = (uint16_t)((cell_coord(pc[3*idx+2]) << 6) |
                                (cell_coord(pc[3*idx+1]) << 3) |
                                 cell_coord(pc[3*idx]));
            sm.cellS[idx] = cv;
        }
        __syncthreads();
        const int wid = tid >> 6, lane = tid & 63;
        const int hc = bid * 4 + wid;
        const int hx = hc & 7, hy = (hc >> 3) & 7, hz = hc >> 6;
        const int bx0 = max(hx-1,0), bx1 = min(hx+1,7);
        const int by0 = max(hy-1,0), by1 = min(hy+1,7);
        const int bz0 = max(hz-1,0), bz1 = min(hz+1,7);
        int off = 0;
        for (int it = 0; it < 63; ++it) {
            const int j = it * 64 + lane;
            const uint16_t cid = sm.cellS[j];
            const int cx = cid & 7, cy = (cid >> 3) & 7, cz = cid >> 6;
            const bool in = (j < NCOARSE) && cx >= bx0 && cx <= bx1 &&
                            cy >= by0 && cy <= by1 && cz >= bz0 && cz <= bz1;
            const unsigned long long mask = __ballot(in);
            if (in) {
                const int d = off + (int)__popcll(mask & ((1ull << lane) - 1ull));
                if (d < FCAP)
                    flatC[hc * FCAP + d] =
                        make_float4(pc[3*j], pc[3*j+1], pc[3*j+2], __int_as_float(j));
            }
            off += (int)__popcll(mask);
        }
        if (lane == 0) nbrCnt[hc] = off;     // write-once: no zeroing, no atomics
    } else {
        // ---- Y-GEMM tile: 32 rows x 128 cols
        const int g  = bid - NB_B;
        const int r0 = g * 32;
        #pragma unroll
        for (int t = 0; t < 4; ++t)
            reinterpret_cast<float4*>(sm.xs)[tid + t * 256] =
                reinterpret_cast<const float4*>(xc + r0 * DIM)[tid + t * 256];
        __syncthreads();
        const int rq = tid >> 5;
        const int jq = tid & 31;
        float acc[4][4];
        #pragma unroll
        for (int i = 0; i < 4; ++i)
            #pragma unroll
            for (int j = 0; j < 4; ++j) acc[i][j] = 0.f;
        #pragma unroll 2
        for (int k = 0; k < DIM; ++k) {
            const float4 wv = *reinterpret_cast<const float4*>(W + k * DIM + jq * 4);
            #pragma unroll
            for (int i = 0; i < 4; ++i) {
                const float a = sm.xs[rq + 8 * i][k];
                acc[i][0] += a * wv.x; acc[i][1] += a * wv.y;
                acc[i][2] += a * wv.z; acc[i][3] += a * wv.w;
            }
        }
        #pragma unroll
        for (int i = 0; i < 4; ++i)
            *reinterpret_cast<float4*>(Y + (r0 + rq + 8 * i) * DIM + jq * 4) =
                make_float4(acc[i][0], acc[i][1], acc[i][2], acc[i][3]);
    }
}

// ---------------- main: 16-lane flat-list KNN + gather-mean of Y ----------------
// exact top-7 of the union of 16 lanes' sorted 7-lists via 7-round pop-min.
__device__ __forceinline__ void popmin_merge(const uint64_t own[7], uint64_t mg[7]) {
    uint64_t a0 = own[0], a1 = own[1], a2 = own[2], a3 = own[3],
             a4 = own[4], a5 = own[5], a6 = own[6];
    #pragma unroll
    for (int r = 0; r < 7; ++r) {
        uint64_t m = a0;
        m = min64(m, __shfl_xor((unsigned long long)m, 1));
        m = min64(m, __shfl_xor((unsigned long long)m, 2));
        m = min64(m, __shfl_xor((unsigned long long)m, 4));
        m = min64(m, __shfl_xor((unsigned long long)m, 8));
        mg[r] = m;
        const bool win = (a0 == m);      // unique keys -> at most one real winner
        a0 = win ? a1 : a0;
        a1 = win ? a2 : a1;
        a2 = win ? a3 : a2;
        a3 = win ? a4 : a3;
        a4 = win ? a5 : a4;
        a5 = win ? a6 : a5;
        a6 = win ? ~0ull : a6;
    }
}

__device__ __forceinline__ bool done_check(uint64_t k7, float fx, float fy, float fz,
                                           int ix, int iy, int iz, int s) {
    const float d7 = __uint_as_float((uint32_t)(k7 >> 32));
    float clear = 1e30f;
    if (ix - s >= 0) clear = fminf(clear, __fsub_rn(fx, (float)(ix - s) * CELLH));
    if (ix + s <= 6) clear = fminf(clear, __fsub_rn((float)(ix + s + 1) * CELLH, fx));
    if (iy - s >= 0) clear = fminf(clear, __fsub_rn(fy, (float)(iy - s) * CELLH));
    if (iy + s <= 6) clear = fminf(clear, __fsub_rn((float)(iy + s + 1) * CELLH, fy));
    if (iz - s >= 0) clear = fminf(clear, __fsub_rn(fz, (float)(iz - s) * CELLH));
    if (iz + s <= 6) clear = fminf(clear, __fsub_rn((float)(iz + s + 1) * CELLH, fz));
    return d7 < clear * clear * 0.9999f;   // NaN sentinel -> false
}

// branchless insert: if v >= a[6] the network provably leaves the list unchanged
#define INS(p) { \
    const float ddx = __fsub_rn(fx, (p).x); \
    const float ddy = __fsub_rn(fy, (p).y); \
    const float ddz = __fsub_rn(fz, (p).z); \
    const float d2  = __fadd_rn(__fadd_rn(__fmul_rn(ddx, ddx), __fmul_rn(ddy, ddy)), \
                                __fmul_rn(ddz, ddz)); \
    const uint64_t v = ((uint64_t)__float_as_uint(d2) << 32) | (uint32_t)__float_as_uint((p).w); \
    own[6] = min64(own[6], max64(own[5], v)); \
    own[5] = min64(own[5], max64(own[4], v)); \
    own[4] = min64(own[4], max64(own[3], v)); \
    own[3] = min64(own[3], max64(own[2], v)); \
    own[2] = min64(own[2], max64(own[1], v)); \
    own[1] = min64(own[1], max64(own[0], v)); \
    own[0] = min64(own[0], v); \
    }

#define BRUTE() { \
    _Pragma("unroll") \
    for (int r = 0; r < 7; ++r) own[r] = ~0ull; \
    for (int i = par; i < NCOARSE; i += LPP) { \
        const float4 p = make_float4(pc[3*i], pc[3*i+1], pc[3*i+2], __int_as_float(i)); \
        INS(p) \
    } }

__global__ __launch_bounds__(256) void k_main(
    const float*  __restrict__ Y,        // [4000][128] = xc @ W
    const float*  __restrict__ bias,
    const int*    __restrict__ nbrCnt,
    const float4* __restrict__ flatC,    // per-home-cell flat candidate lists
    const float*  __restrict__ pc,       // raw coarse positions (brute fallback)
    const float*  __restrict__ pf,
    float* __restrict__ out)
{
    const int tid = threadIdx.x;
    const int fl  = tid >> 4;        // 0..15 local fine point
    const int par = tid & 15;        // lane within point-group
    const int f   = blockIdx.x * 16 + fl;

    const float fx = pf[3*f], fy = pf[3*f+1], fz = pf[3*f+2];
    const int ix = cell_coord(fx), iy = cell_coord(fy), iz = cell_coord(fz);
    const int cell = (iz << 6) | (iy << 3) | ix;

    const int total = nbrCnt[cell];

    uint64_t own[7];
    #pragma unroll
    for (int r = 0; r < 7; ++r) own[r] = ~0ull;
    uint64_t mg[7];

    if (total <= FCAP) {
        const float4* fpts = flatC + cell * FCAP;
        #pragma unroll 2
        for (int i = par; i < total; i += LPP) { const float4 p = fpts[i]; INS(p) }
        popmin_merge(own, mg);
        if (!done_check(mg[6], fx, fy, fz, ix, iy, iz, 1)) {   // ~never (P<1e-9/pt)
            BRUTE();
            popmin_merge(own, mg);
        }
    } else {                                     // flat list overflowed (~never)
        BRUTE();
        popmin_merge(own, mg);
    }

    // 6th/7th sqrt tie repair (reference sorts by f32 sqrt, stable) — uniform per group
    int i5 = (int)(uint32_t)mg[5];
    {
        const int i6 = (int)(uint32_t)mg[6];
        const float d5 = sqrtf(__uint_as_float((uint32_t)(mg[5] >> 32)));
        const float d6 = sqrtf(__uint_as_float((uint32_t)(mg[6] >> 32)));
        if (d5 == d6 && i6 < i5) i5 = i6;
    }
    const int id0 = (int)(uint32_t)mg[0];
    const int id1 = (int)(uint32_t)mg[1];
    const int id2 = (int)(uint32_t)mg[2];
    const int id3 = (int)(uint32_t)mg[3];
    const int id4 = (int)(uint32_t)mg[4];
    const int id5 = i5;

    // epilogue: out[f] = mean(Y[idx6]) + b ; lane par covers 8 dims (2 float4)
    constexpr float inv6 = 1.0f / 6.0f;
    const int q0 = par * 8;
    #pragma unroll
    for (int h = 0; h < 2; ++h) {
        const int q = q0 + h * 4;
        const float4 y0 = *reinterpret_cast<const float4*>(Y + id0 * DIM + q);
        const float4 y1 = *reinterpret_cast<const float4*>(Y + id1 * DIM + q);
        const float4 y2 = *reinterpret_cast<const float4*>(Y + id2 * DIM + q);
        const float4 y3 = *reinterpret_cast<const float4*>(Y + id3 * DIM + q);
        const float4 y4 = *reinterpret_cast<const float4*>(Y + id4 * DIM + q);
        const float4 y5 = *reinterpret_cast<const float4*>(Y + id5 * DIM + q);
        const float4 bv = *reinterpret_cast<const float4*>(bias + q);
        float4 o;
        o.x = (y0.x + y1.x + y2.x + y3.x + y4.x + y5.x) * inv6 + bv.x;
        o.y = (y0.y + y1.y + y2.y + y3.y + y4.y + y5.y) * inv6 + bv.y;
        o.z = (y0.z + y1.z + y2.z + y3.z + y4.z + y5.z) * inv6 + bv.z;
        o.w = (y0.w + y1.w + y2.w + y3.w + y4.w + y5.w) * inv6 + bv.w;
        *reinterpret_cast<float4*>(out + f * DIM + q) = o;
    }
}

extern "C" void kernel_launch(void* const* d_in, const int* in_sizes, int n_in,
                              void* d_out, int out_size, void* d_ws, size_t ws_size,
                              hipStream_t stream) {
    const float* xc = (const float*)d_in[0];
    const float* pc = (const float*)d_in[1];
    const float* pf = (const float*)d_in[2];
    const float* W  = (const float*)d_in[3];
    const float* b  = (const float*)d_in[4];
    float* out = (float*)d_out;

    // ws layout (bytes):
    //   0        nbrCnt  512 ints (2048, pad to 4096)
    //   4096     flatC   512*384 float4 (3145728)
    //   3149824  Y       4000*128 f32   (2048000)   total 5197824
    int*    nbrCnt = (int*)d_ws;
    float4* flatC  = (float4*)((char*)d_ws + 4096);
    float*  Y      = (float*)((char*)d_ws + 3149824);

    k_build<<<dim3(NBUILD),       dim3(256), 0, stream>>>(pc, xc, W, nbrCnt, flatC, Y);
    k_main <<<dim3(NFINE / LPP),  dim3(256), 0, stream>>>(Y, b, nbrCnt, flatC, pc, pf, out);
}